// Round 9
// baseline (159.694 us; speedup 1.0000x reference)
//
#include <hip/hip_runtime.h>

// Mo3ENet neighbor selection: B=256, PER=1024, NIN=256, NOUT=768, K=32, R=6
// Round 9: lane-per-target decomposition. wave = 64 targets x 1 candidate
// split (8 splits/target: ii 32 cands, io 96 cands). Candidates broadcast
// from LDS (wave-uniform addr). Two passes: count -> prefix -> write hits
// into per-target LDS slot rows; pad slots from inverted predicate with
// derived prefix. Coalesced 4-array epilogue.
// Outputs (concatenated float32):
//   [0) src_ii | [E) tgt | [2E) m_ii | [3E) dist_ii |
//   [4E) src_io | [5E) tgt | [6E) m_io | [7E) dist_io

constexpr int KK = 32;
constexpr unsigned EE = 2097152u;  // elements per output array

typedef float v2f __attribute__((ext_vector_type(2)));

// Distance^2 of lane's target (xi,yi,zi) to candidates c and c+1 (broadcast).
// contract(off) + op order ((dx^2+dy^2)+dz^2) == reference bitwise per half.
// Predicate d2 < 36.0f is bit-identical to sqrtf(d2) < 6.0f (f32).
__device__ __forceinline__ v2f d2pair(const float* __restrict__ sq, int c,
                                      float xi, float yi, float zi) {
#pragma clang fp contract(off)
    const float x0 = sq[3 * c],     y0 = sq[3 * c + 1], z0 = sq[3 * c + 2];
    const float x1 = sq[3 * c + 3], y1 = sq[3 * c + 4], z1 = sq[3 * c + 5];
    v2f dx = (v2f){x0, x1} - (v2f){xi, xi};
    v2f dy = (v2f){y0, y1} - (v2f){yi, yi};
    v2f dz = (v2f){z0, z1} - (v2f){zi, zi};
    return (dx * dx + dy * dy) + dz * dz;
}

__global__ __launch_bounds__(512, 8) void mo3e_kernel(const float* __restrict__ pos,
                                                      float* __restrict__ out) {
    __shared__ float sq[3072];        // 12 KB: batch positions, xyz flat
    __shared__ int   hii[64 * 32];    // 8 KB: ii slot rows (batch-local cand idx)
    __shared__ int   hio[64 * 32];    // 8 KB: io slot rows
    __shared__ int   cnts[2][8][64];  // 4 KB: per-split valid counts
    __shared__ int   tots[2][64];     // 512 B: S0 per target (clamped totals)

    const int blk = blockIdx.x;
    const int b   = blk >> 2;          // 4 blocks per batch
    const int T0  = (blk & 3) << 6;    // 64 targets per block
    const int tid = threadIdx.x;
    const int tl  = tid & 63;          // lane = target-local
    const int q   = tid >> 6;          // split 0..7 (wave-uniform)
    const int i   = T0 + tl;           // batch-local target index

    // Stage batch positions (768 float4), coalesced.
    {
        const float4* g4 = (const float4*)(pos + (size_t)b * 3072);
        float4* s4 = (float4*)sq;
        s4[tid] = g4[tid];
        if (tid < 256) s4[tid + 512] = g4[tid + 512];
    }
    __syncthreads();

    const float xi = sq[3 * i], yi = sq[3 * i + 1], zi = sq[3 * i + 2];

    // ---------------- pass A: count valids in this thread's splits ----------------
    int cii = 0;
    {
        const int c0 = q << 5;                       // ii split: [32q, 32q+32)
#pragma unroll
        for (int m = 0; m < 16; ++m) {
            const int c = c0 + 2 * m;
            const v2f d2 = d2pair(sq, c, xi, yi, zi);
            cii += (int)((d2.x < 36.0f) & (c != i));
            cii += (int)((d2.y < 36.0f) & ((c + 1) != i));
        }
    }
    int cio = 0;
    {
        const int c0 = 256 + 96 * q;                 // io split: [256+96q, +96)
#pragma unroll 8
        for (int m = 0; m < 48; ++m) {
            const int c = c0 + 2 * m;
            const v2f d2 = d2pair(sq, c, xi, yi, zi);
            cio += (int)(d2.x < 36.0f);
            cio += (int)(d2.y < 36.0f);
        }
    }
    cnts[0][q][tl] = cii;
    cnts[1][q][tl] = cio;
    __syncthreads();

    // ---------------- prefix sums over splits ----------------
    int pii = 0, Sii = 0, pio = 0, Sio = 0;
#pragma unroll
    for (int qq = 0; qq < 8; ++qq) {
        const int a = cnts[0][qq][tl];
        const int d = cnts[1][qq][tl];
        if (qq < q) { pii += a; pio += d; }
        Sii += a; Sio += d;
    }
    const int S0ii = Sii < KK ? Sii : KK;
    const int S0io = Sio < KK ? Sio : KK;
    if (q == 0) { tots[0][tl] = S0ii; tots[1][tl] = S0io; }  // visible after next barrier

    // ---------------- pass B: write hits (slots disjoint across splits) ----------------
    {   // ii main
        const int c0 = q << 5;
        int r = pii;
#pragma unroll
        for (int m = 0; m < 16; ++m) {
            const int c = c0 + 2 * m;
            const v2f d2 = d2pair(sq, c, xi, yi, zi);
            const bool va = (d2.x < 36.0f) & (c != i);
            if (va && r < KK) hii[(tl << 5) + r] = c;
            r += va;
            const bool vb = (d2.y < 36.0f) & ((c + 1) != i);
            if (vb && r < KK) hii[(tl << 5) + r] = c + 1;
            r += vb;
        }
        // ii pad: invalid cands (incl. c==i), ascending; prefix = 32q - pii
        int pr = S0ii + (q << 5) - pii;
        if (pr < KK) {
#pragma unroll
            for (int m = 0; m < 16; ++m) {
                const int c = c0 + 2 * m;
                const v2f d2 = d2pair(sq, c, xi, yi, zi);
                const bool ia = !((d2.x < 36.0f) & (c != i));
                if (ia && pr < KK) hii[(tl << 5) + pr] = c;
                pr += ia;
                const bool ib = !((d2.y < 36.0f) & ((c + 1) != i));
                if (ib && pr < KK) hii[(tl << 5) + pr] = c + 1;
                pr += ib;
            }
        }
    }
    {   // io main
        const int c0 = 256 + 96 * q;
        int r = pio;
#pragma unroll 8
        for (int m = 0; m < 48; ++m) {
            const int c = c0 + 2 * m;
            const v2f d2 = d2pair(sq, c, xi, yi, zi);
            const bool va = (d2.x < 36.0f);
            if (va && r < KK) hio[(tl << 5) + r] = c;
            r += va;
            const bool vb = (d2.y < 36.0f);
            if (vb && r < KK) hio[(tl << 5) + r] = c + 1;
            r += vb;
        }
        // io pad: prefix of invalids = 96q - pio
        int pr = S0io + 96 * q - pio;
        if (pr < KK) {
#pragma unroll 8
            for (int m = 0; m < 48; ++m) {
                const int c = c0 + 2 * m;
                const v2f d2 = d2pair(sq, c, xi, yi, zi);
                const bool ia = !(d2.x < 36.0f);
                if (ia && pr < KK) hio[(tl << 5) + pr] = c;
                pr += ia;
                const bool ib = !(d2.y < 36.0f);
                if (ib && pr < KK) hio[(tl << 5) + pr] = c + 1;
                pr += ib;
            }
        }
    }
    __syncthreads();

    // ---------------- epilogue: fully coalesced stores ----------------
    // item id = target-local row-major slot; out offset is linear in id.
    const unsigned base = ((unsigned)(b * 256 + T0)) << 5;
    const int goff = b << 10;
#pragma unroll
    for (int e = 0; e < 4; ++e) {
        const int id = (e << 9) + tid;         // 0..2047
        const int t  = id >> 5, k = id & 31;
        const int ig = T0 + t;
        const float xt = sq[3 * ig], yt = sq[3 * ig + 1], zt = sq[3 * ig + 2];
        const float tv = (float)(goff + ig);
        {   // ii row
            const int c = hii[id];
            const float dx = xt - sq[3 * c], dy = yt - sq[3 * c + 1], dz = zt - sq[3 * c + 2];
            const float d2 = dx * dx + dy * dy + dz * dz;   // dist tol loose: any order
            const bool mv = k < tots[0][t];
            out[base + id]           = (float)(goff + c);
            out[base + id + EE]      = tv;
            out[base + id + 2u * EE] = mv ? 1.0f : 0.0f;
            out[base + id + 3u * EE] = mv ? __builtin_amdgcn_sqrtf(d2) : 0.0f;
        }
        {   // io row (cand idx already in [256,1024) == NIN + idx_io)
            const int c = hio[id];
            const float dx = xt - sq[3 * c], dy = yt - sq[3 * c + 1], dz = zt - sq[3 * c + 2];
            const float d2 = dx * dx + dy * dy + dz * dz;
            const bool mv = k < tots[1][t];
            out[base + id + 4u * EE] = (float)(goff + c);
            out[base + id + 5u * EE] = tv;
            out[base + id + 6u * EE] = mv ? 1.0f : 0.0f;
            out[base + id + 7u * EE] = mv ? __builtin_amdgcn_sqrtf(d2) : 0.0f;
        }
    }
}

extern "C" void kernel_launch(void* const* d_in, const int* in_sizes, int n_in,
                              void* d_out, int out_size, void* d_ws, size_t ws_size,
                              hipStream_t stream) {
    const float* pos = (const float*)d_in[0];
    float* out = (float*)d_out;

    // 4 blocks/batch x 256 batches; 512 threads = 8 waves = 64 targets x 8 splits.
    mo3e_kernel<<<dim3(1024), dim3(512), 0, stream>>>(pos, out);
}

// Round 10
// 114.981 us; speedup vs baseline: 1.3889x; 1.3889x over previous
//
#include <hip/hip_runtime.h>

// Mo3ENet neighbor selection: B=256, PER=1024, NIN=256, NOUT=768, K=32, R=6
// Round 10: 4 targets per wave. Candidate coords loaded once per wave per
// group (pair-SoA ds_read_b64), reused by 4 targets (pre-negated uniform
// coords + pk asm math). Ballot compaction with direct scattered global
// stores (r4 showed no write amplification). ii pad via saved masks; io pad
// recomputes. Outputs (concatenated float32):
//   [0) src_ii | [E) tgt | [2E) m_ii | [3E) dist_ii |
//   [4E) src_io | [5E) tgt | [6E) m_io | [7E) dist_io

constexpr int KK = 32;
constexpr unsigned EE = 2097152u;  // elements per output array

typedef float v2f __attribute__((ext_vector_type(2)));

__device__ __forceinline__ v2f pk_add(v2f a, v2f b) {
    v2f d; asm("v_pk_add_f32 %0, %1, %2" : "=v"(d) : "v"(a), "v"(b)); return d;
}
__device__ __forceinline__ v2f pk_mul(v2f a, v2f b) {
    v2f d; asm("v_pk_mul_f32 %0, %1, %2" : "=v"(d) : "v"(a), "v"(b)); return d;
}

__device__ __forceinline__ int prefix_lt(unsigned long long m) {
    return __builtin_amdgcn_mbcnt_hi((unsigned)(m >> 32),
           __builtin_amdgcn_mbcnt_lo((unsigned)m, 0u));
}

// pair-SoA float index of point j: v2f slot ((j>>7)*64 + (j&63)), half (j>>6)&1
__device__ __forceinline__ int fo_of(int j) {
    return ((((j >> 7) << 6) | (j & 63)) << 1) | ((j >> 6) & 1);
}

__global__ __launch_bounds__(256) void mo3e_kernel(const float* __restrict__ pos,
                                                   float* __restrict__ out) {
    __shared__ v2f sqx[512], sqy[512], sqz[512];  // 12 KB pair-SoA coords

    const int blk = blockIdx.x;
    const int b   = blk >> 4;           // 16 blocks per batch
    const int tid = threadIdx.x;
    const int w   = tid >> 6;
    const int l   = tid & 63;
    // first of this wave's 4 targets (wave-uniform scalar)
    const int t0 = __builtin_amdgcn_readfirstlane(((blk & 15) << 4) | (w << 2));

    // ---- stage: 4 points per thread (12 consecutive floats = 3 float4) ----
    {
        const float4* g4 = (const float4*)(pos + (size_t)b * 3072);
        const float4 A = g4[3 * tid], Bq = g4[3 * tid + 1], C = g4[3 * tid + 2];
        float* fx = (float*)sqx; float* fy = (float*)sqy; float* fz = (float*)sqz;
        const float px[4] = {A.x, A.w, Bq.z, C.y};
        const float py[4] = {A.y, Bq.x, Bq.w, C.z};
        const float pz[4] = {A.z, Bq.y, C.x, C.w};
#pragma unroll
        for (int u = 0; u < 4; ++u) {
            const int fo = fo_of(4 * tid + u);
            fx[fo] = px[u]; fy[fo] = py[u]; fz[fo] = pz[u];
        }
    }
    __syncthreads();

    // ---- per-target uniform state ----
    const int goff = b << 10;
    v2f nx[4], ny[4], nz[4];
    int gself[4];
    unsigned e0[4];
    int cii[4] = {0, 0, 0, 0}, cio[4] = {0, 0, 0, 0};
    unsigned long long mii[4][4];  // saved ii masks for pad
#pragma unroll
    for (int t = 0; t < 4; ++t) {
        const int it = t0 + t;
        const int fo = fo_of(it);
        const float x = ((float*)sqx)[fo], y = ((float*)sqy)[fo], z = ((float*)sqz)[fo];
        nx[t] = (v2f){-x, -x}; ny[t] = (v2f){-y, -y}; nz[t] = (v2f){-z, -z};
        gself[t] = it >> 6;
        e0[t] = (unsigned)((b << 8) + it) << 5;
    }

    // ---- main scan: 8 pair-groups x 4 targets ----
    // predicate: d2 < 36.0f with d2 = ((q-xi)^2+(q-yi)^2)+(q-zi)^2 per half;
    // (q-t)^2 == (t-q)^2 bitwise, op order matches reference, asm pk ops
    // cannot be contracted; d2<36 is bit-identical to sqrt(d2)<6 in f32.
#pragma unroll
    for (int p = 0; p < 8; ++p) {
        const v2f qx = sqx[(p << 6) + l], qy = sqy[(p << 6) + l], qz = sqz[(p << 6) + l];
#pragma unroll
        for (int t = 0; t < 4; ++t) {
            const v2f dx = pk_add(qx, nx[t]), dy = pk_add(qy, ny[t]), dz = pk_add(qz, nz[t]);
            const v2f d2 = pk_add(pk_add(pk_mul(dx, dx), pk_mul(dy, dy)), pk_mul(dz, dz));
#pragma unroll
            for (int h = 0; h < 2; ++h) {
                const int g = 2 * p + h;             // 64-cand group, cand j = g*64+l
                const float d2h = h ? d2.y : d2.x;
                unsigned long long ms = __ballot(d2h < 36.0f);
                if (g < 4 && g == gself[t]) ms &= ~(1ull << ((t0 + t) & 63));
                const int cnt = (g < 4) ? cii[t] : cio[t];
                const int slot = cnt + prefix_lt(ms);
                if (((ms >> l) & 1ull) && slot < KK) {
                    const unsigned base = e0[t] + (g < 4 ? 0u : 4u * EE);
                    out[base + slot]           = (float)(goff + (g << 6) + l);
                    out[base + slot + 3u * EE] = __builtin_amdgcn_sqrtf(d2h);
                }
                const int ncnt = cnt + (int)__popcll(ms);
                if (g < 4) { cii[t] = ncnt; mii[t][g] = ms; } else cio[t] = ncnt;
            }
        }
    }

    // ---- epilogue per target: rows + pads ----
#pragma unroll
    for (int t = 0; t < 4; ++t) {
        const int it = t0 + t;
        const int S0a = cii[t] < KK ? cii[t] : KK;
        const int S0b = cio[t] < KK ? cio[t] : KK;
        const float tv = (float)(goff + it);
        if (l < KK) {
            out[e0[t] + l + EE]      = tv;                         // tgt_ii
            out[e0[t] + l + 5u * EE] = tv;                         // tgt_io
            out[e0[t] + l + 2u * EE] = (l < S0a) ? 1.0f : 0.0f;    // m_ii
            out[e0[t] + l + 6u * EE] = (l < S0b) ? 1.0f : 0.0f;    // m_io
            if (l >= S0a) out[e0[t] + l + 3u * EE] = 0.0f;         // dist_ii pad
            if (l >= S0b) out[e0[t] + l + 7u * EE] = 0.0f;         // dist_io pad
        }
        // ii pad: smallest invalid indices (incl. j==i), from saved masks
        if (S0a < KK) {
            int pc = S0a;
#pragma unroll
            for (int g = 0; g < 4; ++g) {
                const unsigned long long inv = ~mii[t][g];
                const int slot = pc + prefix_lt(inv);
                if (((inv >> l) & 1ull) && slot < KK)
                    out[e0[t] + slot] = (float)(goff + (g << 6) + l);
                pc += (int)__popcll(inv);
                if (pc >= KK) break;   // invalids dense: ~1 iteration
            }
        }
        // io pad: recompute predicate (wave-uniform branch; converged ballot ok)
        if (S0b < KK) {
            int pc = S0b;
            for (int p = 2; p < 8; ++p) {
                const v2f qx = sqx[(p << 6) + l], qy = sqy[(p << 6) + l], qz = sqz[(p << 6) + l];
                const v2f dx = pk_add(qx, nx[t]), dy = pk_add(qy, ny[t]), dz = pk_add(qz, nz[t]);
                const v2f d2 = pk_add(pk_add(pk_mul(dx, dx), pk_mul(dy, dy)), pk_mul(dz, dz));
#pragma unroll
                for (int h = 0; h < 2; ++h) {
                    const float d2h = h ? d2.y : d2.x;
                    const unsigned long long inv = ~__ballot(d2h < 36.0f);
                    const int slot = pc + prefix_lt(inv);
                    if (((inv >> l) & 1ull) && slot < KK)
                        out[e0[t] + 4u * EE + slot] = (float)(goff + (p << 7) + (h << 6) + l);
                    pc += (int)__popcll(inv);
                }
                if (pc >= KK) break;   // ~62 invalid per group: ~1 iteration
            }
        }
    }
}

extern "C" void kernel_launch(void* const* d_in, const int* in_sizes, int n_in,
                              void* d_out, int out_size, void* d_ws, size_t ws_size,
                              hipStream_t stream) {
    const float* pos = (const float*)d_in[0];
    float* out = (float*)d_out;

    // 16 blocks/batch x 256 batches; 256 threads = 4 waves x 4 targets = 16 targets/block.
    mo3e_kernel<<<dim3(4096), dim3(256), 0, stream>>>(pos, out);
}

// Round 11
// 103.776 us; speedup vs baseline: 1.5388x; 1.1080x over previous
//
#include <hip/hip_runtime.h>

// Mo3ENet neighbor selection: B=256, PER=1024, NIN=256, NOUT=768, K=32, R=6
// Round 11: r8 skeleton (ballot compaction -> LDS slot rows -> coalesced
// epilogue) with 2 targets per wave sharing candidate coord reads, and
// single-group pads (if S0<K, the first group of a section always holds
// >= 33 invalids >= K-S0, so pads come entirely from group 0 / group 4).
// Outputs (concatenated float32):
//   [0) src_ii | [E) tgt | [2E) m_ii | [3E) dist_ii |
//   [4E) src_io | [5E) tgt | [6E) m_io | [7E) dist_io
//
// Per-wave, per-target LDS slot row (128 ints): [0..31] ii | [32..63] io |
// [64..127] dead (dump + spill). Conditional writes use (mine && e<K) so
// spills always land in the dead region regardless of phase order.

constexpr int KK = 32;
constexpr unsigned EE = 2097152u;  // elements per output array

typedef float v2f __attribute__((ext_vector_type(2)));

__device__ __forceinline__ v2f pk_add(v2f a, v2f b) {
    v2f d; asm("v_pk_add_f32 %0, %1, %2" : "=v"(d) : "v"(a), "v"(b)); return d;
}
__device__ __forceinline__ v2f pk_mul(v2f a, v2f b) {
    v2f d; asm("v_pk_mul_f32 %0, %1, %2" : "=v"(d) : "v"(a), "v"(b)); return d;
}

__device__ __forceinline__ int prefix_lt(unsigned long long m) {
    return __builtin_amdgcn_mbcnt_hi((unsigned)(m >> 32),
           __builtin_amdgcn_mbcnt_lo((unsigned)m, 0u));
}

__global__ __launch_bounds__(256) void mo3e_kernel(const float* __restrict__ pos,
                                                   float* __restrict__ out) {
    __shared__ float sq[3072];            // flat xyz, 12 KB
    __shared__ int   slotrow[4][2][128];  // 4 KB: per wave x per target

    const int blk = blockIdx.x;
    const int b   = blk >> 5;             // 32 blocks per batch
    const int tid = threadIdx.x;
    const int w   = tid >> 6;
    const int l   = tid & 63;
    // first of this wave's 2 targets (even, wave-uniform scalar)
    const int i0  = __builtin_amdgcn_readfirstlane(((blk & 31) << 3) | (w << 1));

    // Stage batch positions: 3 coalesced float4 per thread (r8 verbatim).
    {
        const float4* g4 = (const float4*)(pos + (size_t)b * 3072);
        float4* s4 = (float4*)sq;
        s4[tid      ] = g4[tid      ];
        s4[tid + 256] = g4[tid + 256];
        s4[tid + 512] = g4[tid + 512];
    }
    __syncthreads();

    const float x0 = sq[3 * i0],     y0 = sq[3 * i0 + 1], z0 = sq[3 * i0 + 2];
    const float x1 = sq[3 * i0 + 3], y1 = sq[3 * i0 + 4], z1 = sq[3 * i0 + 5];
    // (q + (-t)) == (q - t); (q-t)^2 == (t-q)^2 bitwise. Per-half op order
    // (dx^2+dy^2)+dz^2 matches the reference; asm pk ops cannot be
    // contracted. Predicate d2 < 36.0f is bit-identical to sqrt(d2) < 6.
    const v2f nx[2] = {{-x0, -x0}, {-x1, -x1}};
    const v2f ny[2] = {{-y0, -y0}, {-y1, -y1}};
    const v2f nz[2] = {{-z0, -z0}, {-z1, -z1}};

    int* const rows[2] = { slotrow[w][0], slotrow[w][1] };
    const int dump = 64 + l;              // per-lane dead entry
    const int gs   = i0 >> 6;             // ii group containing both selves

    unsigned long long m0ii[2], m0io[2];  // group-0 / group-4 masks for pads
    int cii[2] = {0, 0}, cio[2] = {0, 0};

    // ---- main scan: 8 iters x 2 cands/lane, both targets share the reads ----
    int av = 3 * l;                       // dword index of cand (it*128 + l)
#pragma unroll
    for (int it = 0; it < 8; ++it) {
        const float xa = sq[av], ya = sq[av + 1], za = sq[av + 2];
        const float xb = sq[av + 192], yb = sq[av + 193], zb = sq[av + 194];
        av += 384;
        const v2f qx = {xa, xb}, qy = {ya, yb}, qz = {za, zb};
#pragma unroll
        for (int T = 0; T < 2; ++T) {
            const v2f dx = pk_add(qx, nx[T]), dy = pk_add(qy, ny[T]), dz = pk_add(qz, nz[T]);
            const v2f d2 = pk_add(pk_add(pk_mul(dx, dx), pk_mul(dy, dy)), pk_mul(dz, dz));
#pragma unroll
            for (int h = 0; h < 2; ++h) {
                const int g = 2 * it + h;          // 64-cand group; cand = g*64+l
                const float dh = h ? d2.y : d2.x;
                unsigned long long ms = __ballot(dh < 36.0f);
                if (g < 4 && g == gs) ms &= ~(1ull << ((i0 & 63) + T));  // self
                const bool mine = (ms >> l) & 1ull;
                if (g < 4) {                       // ii section
                    const int e = cii[T] + prefix_lt(ms);
                    const bool wr = mine && (e < KK);
                    rows[T][wr ? e : dump] = (g << 6) + l;
                    cii[T] += (int)__popcll(ms);
                    if (g == 0) m0ii[T] = ms;
                } else {                           // io section
                    const int e = cio[T] + prefix_lt(ms);
                    const bool wr = mine && (e < KK);
                    rows[T][wr ? e + KK : dump] = (g << 6) + l;
                    cio[T] += (int)__popcll(ms);
                    if (g == 4) m0io[T] = ms;
                }
            }
        }
    }

    // ---- pads: single group each (always sufficient when S0 < K) ----
#pragma unroll
    for (int T = 0; T < 2; ++T) {
        if (cii[T] < KK) {   // smallest ii invalids are all in group 0
            const unsigned long long inv = ~m0ii[T];
            const int e = cii[T] + prefix_lt(inv);
            const bool wr = ((inv >> l) & 1ull) && (e < KK);
            rows[T][wr ? e : dump] = l;                 // cand = 0*64 + l
        }
        if (cio[T] < KK) {   // smallest io invalids are all in group 4
            const unsigned long long inv = ~m0io[T];
            const int e = cio[T] + prefix_lt(inv);
            const bool wr = ((inv >> l) & 1ull) && (e < KK);
            rows[T][wr ? e + KK : dump] = 256 + l;      // cand = 4*64 + l
        }
    }

    // ---- epilogue: per target, 4 coalesced wave-wide stores ----
    const int goff = b << 10;
#pragma unroll
    for (int T = 0; T < 2; ++T) {
        const int idx = rows[T][l];       // same-wave RAW: lgkmcnt handles it
        const float qx = sq[3 * idx], qy = sq[3 * idx + 1], qz = sq[3 * idx + 2];
        const float xi = T ? x1 : x0, yi = T ? y1 : y0, zi = T ? z1 : z0;
        const float ddx = xi - qx, ddy = yi - qy, ddz = zi - qz;
        const float d2e = ddx * ddx + ddy * ddy + ddz * ddz;  // dist tol loose

        const bool isA = l < KK;
        const int  Sa  = cii[T] < KK ? cii[T] : KK;
        const int  Sb  = cio[T] < KK ? cio[T] : KK;
        const int  S0  = isA ? Sa : Sb;
        const bool mv  = (l & 31) < S0;
        const float dist = mv ? __builtin_amdgcn_sqrtf(d2e) : 0.0f;

        const unsigned e0  = (unsigned)((b << 8) + i0 + T) << 5;
        const unsigned off = (isA ? 0u : 4u * EE - 32u) + e0 + (unsigned)l;

        out[off]           = (float)(goff + idx);      // src (io idx >= 256)
        out[off + EE]      = (float)(goff + i0 + T);   // tgt
        out[off + 2u * EE] = mv ? 1.0f : 0.0f;         // mask
        out[off + 3u * EE] = dist;                     // dist
    }
}

extern "C" void kernel_launch(void* const* d_in, const int* in_sizes, int n_in,
                              void* d_out, int out_size, void* d_ws, size_t ws_size,
                              hipStream_t stream) {
    const float* pos = (const float*)d_in[0];
    float* out = (float*)d_out;

    // 32 blocks/batch x 256 batches; 256 threads = 4 waves x 2 targets.
    mo3e_kernel<<<dim3(8192), dim3(256), 0, stream>>>(pos, out);
}